// Round 1
// baseline (163.632 us; speedup 1.0000x reference)
//
#include <hip/hip_runtime.h>
#include <math.h>

constexpr int B = 2, S = 512, V = 151643;
constexpr int NROWS = B * S;           // 1024
constexpr float TEMP = 2.0f;
constexpr float CE_W = 1.0f, KL_W = 0.5f;
constexpr int BLK = 256;               // 4 waves

// One block per (b,s) row. Single streaming pass with online-softmax updates
// for two temperatures (1 and TEMP=2; exp(d/2) = sqrt(exp(d))), plus sum(x).
__global__ __launch_bounds__(BLK) void row_stats_kernel(
    const float* __restrict__ logits,
    const int*   __restrict__ labels,
    float* __restrict__ nll_out,
    float* __restrict__ slpsum_out)
{
    const int row = blockIdx.x;
    const float* __restrict__ x = logits + (size_t)row * V;
    const int tid = threadIdx.x;

    float m = -INFINITY, s = 0.f, sT = 0.f, sumx = 0.f;

    constexpr int V4 = V >> 2;         // 37910 float4's, tail of 3
    const float4* __restrict__ x4 = reinterpret_cast<const float4*>(x);
    for (int i = tid; i < V4; i += BLK) {
        float4 v = x4[i];
        float vs[4] = {v.x, v.y, v.z, v.w};
        #pragma unroll
        for (int j = 0; j < 4; ++j) {
            float xv = vs[j];
            sumx += xv;
            float nm = fmaxf(m, xv);
            float es = __expf(m - nm);     // 1 if no new max; 0 on first elem
            float ex = __expf(xv - nm);
            s  = s  * es + ex;
            sT = sT * __fsqrt_rn(es) + __fsqrt_rn(ex);
            m  = nm;
        }
    }
    // tail (3 elements)
    for (int i = (V4 << 2) + tid; i < V; i += BLK) {
        float xv = x[i];
        sumx += xv;
        float nm = fmaxf(m, xv);
        float es = __expf(m - nm);
        float ex = __expf(xv - nm);
        s  = s  * es + ex;
        sT = sT * __fsqrt_rn(es) + __fsqrt_rn(ex);
        m  = nm;
    }

    // wave-64 butterfly combine of (m, s, sT) + plain sum for sumx
    #pragma unroll
    for (int off = 32; off >= 1; off >>= 1) {
        float m2  = __shfl_xor(m,   off, 64);
        float s2  = __shfl_xor(s,   off, 64);
        float sT2 = __shfl_xor(sT,  off, 64);
        float sx2 = __shfl_xor(sumx, off, 64);
        float nm = fmaxf(m, m2);
        float e1 = __expf(m - nm), e2 = __expf(m2 - nm);
        s  = s  * e1 + s2  * e2;
        sT = sT * __fsqrt_rn(e1) + sT2 * __fsqrt_rn(e2);
        m  = nm;
        sumx += sx2;
    }

    __shared__ float red[4][4];
    const int wave = tid >> 6, lane = tid & 63;
    if (lane == 0) {
        red[wave][0] = m; red[wave][1] = s; red[wave][2] = sT; red[wave][3] = sumx;
    }
    __syncthreads();
    if (tid == 0) {
        m = red[0][0]; s = red[0][1]; sT = red[0][2]; sumx = red[0][3];
        #pragma unroll
        for (int w = 1; w < 4; ++w) {
            float m2 = red[w][0], s2 = red[w][1], sT2 = red[w][2];
            float nm = fmaxf(m, m2);
            float e1 = __expf(m - nm), e2 = __expf(m2 - nm);
            s  = s  * e1 + s2  * e2;
            sT = sT * __fsqrt_rn(e1) + sT2 * __fsqrt_rn(e2);
            m  = nm;
            sumx += red[w][3];
        }
        const float logZ = m + logf(s);              // log-sum-exp, temp 1
        const int lab  = labels[row];
        const int safe = lab < 0 ? 0 : lab;
        nll_out[row] = logZ - x[safe];
        const float logZT = m * (1.0f / TEMP) + logf(sT);
        slpsum_out[row] = sumx * (1.0f / TEMP) - (float)V * logZT;
    }
}

// One block, 1024 threads: one row per thread, then block reduction.
__global__ __launch_bounds__(1024) void finalize_kernel(
    const float* __restrict__ nll,
    const float* __restrict__ slpsum,
    const int*   __restrict__ labels,
    const int*   __restrict__ amask,
    const float* __restrict__ tlp,
    float* __restrict__ out)
{
    const int t = threadIdx.x;          // NROWS == 1024 == blockDim.x
    const int srow = t % S;             // timestep index

    const int lab = labels[t];
    const bool valid = (lab != -100);
    float ce_n = valid ? nll[t] : 0.f;
    float ce_d = valid ? 1.f : 0.f;

    const float prob = fminf(expf(tlp[srow]), 0.99f);
    const float p = (1.0f - prob) / (float)V;
    const float kl = ((float)V * p * logf(p)) - p * slpsum[t];
    const float msk = (float)amask[t];
    float kl_n = kl * msk;
    float kl_d = msk;

    #pragma unroll
    for (int off = 32; off >= 1; off >>= 1) {
        ce_n += __shfl_xor(ce_n, off, 64);
        ce_d += __shfl_xor(ce_d, off, 64);
        kl_n += __shfl_xor(kl_n, off, 64);
        kl_d += __shfl_xor(kl_d, off, 64);
    }

    __shared__ float red[16][4];
    const int wave = t >> 6, lane = t & 63;
    if (lane == 0) {
        red[wave][0] = ce_n; red[wave][1] = ce_d;
        red[wave][2] = kl_n; red[wave][3] = kl_d;
    }
    __syncthreads();
    if (t == 0) {
        float a = 0.f, b = 0.f, c = 0.f, d = 0.f;
        #pragma unroll
        for (int w = 0; w < 16; ++w) {
            a += red[w][0]; b += red[w][1]; c += red[w][2]; d += red[w][3];
        }
        const float ce  = a / fmaxf(b, 1.0f);
        const float klv = (d > 0.f ? c / d : c) * (TEMP * TEMP);
        out[0] = CE_W * ce + KL_W * klv;
    }
}

extern "C" void kernel_launch(void* const* d_in, const int* in_sizes, int n_in,
                              void* d_out, int out_size, void* d_ws, size_t ws_size,
                              hipStream_t stream) {
    const float* logits = (const float*)d_in[0];
    const float* tlp    = (const float*)d_in[1];
    const int*   labels = (const int*)d_in[2];
    const int*   amask  = (const int*)d_in[3];
    float* out = (float*)d_out;

    float* nll    = (float*)d_ws;
    float* slpsum = nll + NROWS;

    row_stats_kernel<<<NROWS, BLK, 0, stream>>>(logits, labels, nll, slpsum);
    finalize_kernel<<<1, 1024, 0, stream>>>(nll, slpsum, labels, amask, tlp, out);
}

// Round 2
// 114.570 us; speedup vs baseline: 1.4282x; 1.4282x over previous
//
#include <hip/hip_runtime.h>
#include <math.h>

constexpr int B = 2, S = 512, V = 151643;
constexpr int NROWS = B * S;           // 1024
constexpr float TEMP = 2.0f;
constexpr float CE_W = 1.0f, KL_W = 0.5f;
constexpr int BLK = 256;               // 4 waves
constexpr int V4 = V >> 2;             // 37910 float4s (+3 tail floats)
constexpr int MAIN4 = (V4 / (2 * BLK)) * (2 * BLK);   // 37888

// One block per (b,s) row. Single streaming pass. Defer-max: keep reference
// max m fixed, only rescale accumulators when xv > m+8 (rare). Common path:
// e = exp((xv-m)/2); sT += e; s += e*e; sumx += xv.  -> 1 trans/elem.
__global__ __launch_bounds__(BLK) void row_stats_kernel(
    const float* __restrict__ logits,
    const int*   __restrict__ labels,
    float* __restrict__ nll_out,
    float* __restrict__ slpsum_out)
{
    const int row = blockIdx.x;
    const float* __restrict__ x = logits + (size_t)row * V;
    const int tid = threadIdx.x;
    const float4* __restrict__ x4 = reinterpret_cast<const float4*>(x);

    float m = -INFINITY, mthr = -INFINITY;
    float sA[4], tA[4], uA[4], sB[4], tB[4], uB[4];
    #pragma unroll
    for (int j = 0; j < 4; ++j) {
        sA[j] = tA[j] = uA[j] = 0.f;
        sB[j] = tB[j] = uB[j] = 0.f;
    }

    auto upd = [&](float xv, float& sS, float& tS, float& uS) {
        uS += xv;
        if (xv > mthr) {                      // rare (~once per lane)
            float r  = __expf((m - xv) * 0.5f);  // exp(-inf)=0 on first hit
            float r2 = r * r;
            #pragma unroll
            for (int j = 0; j < 4; ++j) {
                tA[j] *= r;  sA[j] *= r2;
                tB[j] *= r;  sB[j] *= r2;
            }
            m = xv; mthr = xv + 8.0f;
        }
        float e = __expf((xv - m) * 0.5f);    // <= e^4
        tS += e;
        sS = fmaf(e, e, sS);
    };

    // main: 74 iterations/lane, 2 float4 loads in flight
    for (int i = tid; i < MAIN4; i += 2 * BLK) {
        float4 a = x4[i];
        float4 b = x4[i + BLK];
        upd(a.x, sA[0], tA[0], uA[0]);
        upd(a.y, sA[1], tA[1], uA[1]);
        upd(a.z, sA[2], tA[2], uA[2]);
        upd(a.w, sA[3], tA[3], uA[3]);
        upd(b.x, sB[0], tB[0], uB[0]);
        upd(b.y, sB[1], tB[1], uB[1]);
        upd(b.z, sB[2], tB[2], uB[2]);
        upd(b.w, sB[3], tB[3], uB[3]);
    }
    // remainder float4s (22 of them)
    if (MAIN4 + tid < V4) {
        float4 a = x4[MAIN4 + tid];
        upd(a.x, sA[0], tA[0], uA[0]);
        upd(a.y, sA[1], tA[1], uA[1]);
        upd(a.z, sA[2], tA[2], uA[2]);
        upd(a.w, sA[3], tA[3], uA[3]);
    }
    // tail floats (3)
    if ((V4 << 2) + tid < V) {
        upd(x[(V4 << 2) + tid], sA[0], tA[0], uA[0]);
    }

    // fold 8 slots (same m within a lane)
    float s = 0.f, sT = 0.f, sumx = 0.f;
    #pragma unroll
    for (int j = 0; j < 4; ++j) {
        s    += sA[j] + sB[j];
        sT   += tA[j] + tB[j];
        sumx += uA[j] + uB[j];
    }

    // wave-64 butterfly (exact merge across differing per-lane m)
    #pragma unroll
    for (int off = 32; off >= 1; off >>= 1) {
        float m2  = __shfl_xor(m,    off, 64);
        float s2  = __shfl_xor(s,    off, 64);
        float sT2 = __shfl_xor(sT,   off, 64);
        float sx2 = __shfl_xor(sumx, off, 64);
        float nm = fmaxf(m, m2);
        float e1 = __expf((m - nm) * 0.5f), e2 = __expf((m2 - nm) * 0.5f);
        s  = s  * (e1 * e1) + s2 * (e2 * e2);
        sT = sT * e1 + sT2 * e2;
        m  = nm;
        sumx += sx2;
    }

    __shared__ float red[4][4];
    const int wave = tid >> 6, lane = tid & 63;
    if (lane == 0) {
        red[wave][0] = m; red[wave][1] = s; red[wave][2] = sT; red[wave][3] = sumx;
    }
    __syncthreads();
    if (tid == 0) {
        m = red[0][0]; s = red[0][1]; sT = red[0][2]; sumx = red[0][3];
        #pragma unroll
        for (int w = 1; w < 4; ++w) {
            float m2 = red[w][0], s2 = red[w][1], sT2 = red[w][2];
            float nm = fmaxf(m, m2);
            float e1 = __expf((m - nm) * 0.5f), e2 = __expf((m2 - nm) * 0.5f);
            s  = s  * (e1 * e1) + s2 * (e2 * e2);
            sT = sT * e1 + sT2 * e2;
            m  = nm;
            sumx += red[w][3];
        }
        const float logZ = m + logf(s);              // log-sum-exp, temp 1
        const int lab  = labels[row];
        const int safe = lab < 0 ? 0 : lab;
        nll_out[row] = logZ - x[safe];
        const float logZT = m * (1.0f / TEMP) + logf(sT);
        slpsum_out[row] = sumx * (1.0f / TEMP) - (float)V * logZT;
    }
}

// One block, 1024 threads: one row per thread, then block reduction.
__global__ __launch_bounds__(1024) void finalize_kernel(
    const float* __restrict__ nll,
    const float* __restrict__ slpsum,
    const int*   __restrict__ labels,
    const int*   __restrict__ amask,
    const float* __restrict__ tlp,
    float* __restrict__ out)
{
    const int t = threadIdx.x;          // NROWS == 1024 == blockDim.x
    const int srow = t % S;             // timestep index

    const int lab = labels[t];
    const bool valid = (lab != -100);
    float ce_n = valid ? nll[t] : 0.f;
    float ce_d = valid ? 1.f : 0.f;

    const float prob = fminf(expf(tlp[srow]), 0.99f);
    const float p = (1.0f - prob) / (float)V;
    const float kl = ((float)V * p * logf(p)) - p * slpsum[t];
    const float msk = (float)amask[t];
    float kl_n = kl * msk;
    float kl_d = msk;

    #pragma unroll
    for (int off = 32; off >= 1; off >>= 1) {
        ce_n += __shfl_xor(ce_n, off, 64);
        ce_d += __shfl_xor(ce_d, off, 64);
        kl_n += __shfl_xor(kl_n, off, 64);
        kl_d += __shfl_xor(kl_d, off, 64);
    }

    __shared__ float red[16][4];
    const int wave = t >> 6, lane = t & 63;
    if (lane == 0) {
        red[wave][0] = ce_n; red[wave][1] = ce_d;
        red[wave][2] = kl_n; red[wave][3] = kl_d;
    }
    __syncthreads();
    if (t == 0) {
        float a = 0.f, b = 0.f, c = 0.f, d = 0.f;
        #pragma unroll
        for (int w = 0; w < 16; ++w) {
            a += red[w][0]; b += red[w][1]; c += red[w][2]; d += red[w][3];
        }
        const float ce  = a / fmaxf(b, 1.0f);
        const float klv = (d > 0.f ? c / d : c) * (TEMP * TEMP);
        out[0] = CE_W * ce + KL_W * klv;
    }
}

extern "C" void kernel_launch(void* const* d_in, const int* in_sizes, int n_in,
                              void* d_out, int out_size, void* d_ws, size_t ws_size,
                              hipStream_t stream) {
    const float* logits = (const float*)d_in[0];
    const float* tlp    = (const float*)d_in[1];
    const int*   labels = (const int*)d_in[2];
    const int*   amask  = (const int*)d_in[3];
    float* out = (float*)d_out;

    float* nll    = (float*)d_ws;
    float* slpsum = nll + NROWS;

    row_stats_kernel<<<NROWS, BLK, 0, stream>>>(logits, labels, nll, slpsum);
    finalize_kernel<<<1, 1024, 0, stream>>>(nll, slpsum, labels, amask, tlp, out);
}